// Round 11
// baseline (141.215 us; speedup 1.0000x reference)
//
#include <hip/hip_runtime.h>
#include <hip/hip_bf16.h>

// ODELSTMCell: B=16384, I=256, H=256, OH=64, 8 fixed dopri5 steps.
// prep_kernel : wsB=[W_ih|W_hh] bf16; Wc=W1@W2 bf16; u=b2@W1^T f32;
//               w1B=W1 bf16; w2B=W2 bf16.
// lstm_kernel : LDS-FREE register GEMM. Block = 64 samples x 1024 gate-cols,
//               8 waves with disjoint 32-h strips -> zero barriers, zero LDS;
//               A/B frags direct from global, compiler-pipelined K-loop.
// ode_kernel  : zero-exchange G-space dopri5 (R10-verified), 8 samples/wave,
//               grid 2048 -> 2 waves/SIMD for latency hiding.

#define B_N 16384
#define H_N 256

typedef __attribute__((ext_vector_type(8))) short short8;          // 8 x bf16
typedef __attribute__((ext_vector_type(4))) unsigned short u16x4;  // 4 x bf16
typedef __attribute__((ext_vector_type(4))) float f32x4;

__device__ __forceinline__ unsigned short f2bf_s(float x) {
  __hip_bfloat16 h = __float2bfloat16(x);
  return *reinterpret_cast<unsigned short*>(&h);
}

__device__ __forceinline__ short8 pack8f(const float* p) {
  const f32x4 a = *(const f32x4*)p;
  const f32x4 b = *(const f32x4*)(p + 4);
  short8 r;
  r[0] = (short)f2bf_s(a[0]); r[1] = (short)f2bf_s(a[1]);
  r[2] = (short)f2bf_s(a[2]); r[3] = (short)f2bf_s(a[3]);
  r[4] = (short)f2bf_s(b[0]); r[5] = (short)f2bf_s(b[1]);
  r[6] = (short)f2bf_s(b[2]); r[7] = (short)f2bf_s(b[3]);
  return r;
}

// two f32x4 registers -> 8 bf16 fragment
__device__ __forceinline__ short8 pack8v(f32x4 a, f32x4 b) {
  short8 r;
  r[0] = (short)f2bf_s(a[0]); r[1] = (short)f2bf_s(a[1]);
  r[2] = (short)f2bf_s(a[2]); r[3] = (short)f2bf_s(a[3]);
  r[4] = (short)f2bf_s(b[0]); r[5] = (short)f2bf_s(b[1]);
  r[6] = (short)f2bf_s(b[2]); r[7] = (short)f2bf_s(b[3]);
  return r;
}

__device__ __forceinline__ float fast_sigmoid(float x) {
  return __builtin_amdgcn_rcpf(1.f + __expf(-x));
}
// clamp-free: e^inf -> rcp 0 -> 1; e^-inf -> 0 -> -1  (exact limits)
__device__ __forceinline__ float fast_tanh(float x) {
  float e = __expf(2.f * x);
  return 1.f - 2.f * __builtin_amdgcn_rcpf(e + 1.f);
}

// ---------------------------------------------------------------------------
// prep: [0,256) wsB; [256,272) Wc=W1@W2; 272 u=b2@W1^T; [273,281) w1B; [281,289) w2B
// ---------------------------------------------------------------------------
__global__ __launch_bounds__(256) void prep_kernel(
    const float* __restrict__ Wih, const float* __restrict__ Whh,
    const float* __restrict__ W1, const float* __restrict__ W2,
    const float* __restrict__ b2,
    unsigned short* __restrict__ wsB, unsigned short* __restrict__ wcB,
    float* __restrict__ uF, unsigned short* __restrict__ w1B,
    unsigned short* __restrict__ w2B) {
  const int bx = blockIdx.x;
  if (bx < 256) {
    int idx = bx * 256 + threadIdx.x;
    int n = idx >> 6, c = idx & 63, k = c * 8;
    const float* src = (k < 256) ? (Wih + (size_t)n * 256 + k)
                                 : (Whh + (size_t)n * 256 + (k - 256));
    *(short8*)(wsB + (size_t)n * 512 + k) = pack8f(src);
  } else if (bx < 272) {
    int idx = (bx - 256) * 256 + threadIdx.x;  // [0,4096)
    int f = idx >> 6, o = idx & 63;
    float a0 = 0.f, a1 = 0.f, a2 = 0.f, a3 = 0.f;
    for (int h = 0; h < 256; h += 4) {
      a0 = fmaf(W1[f * 256 + h],     W2[h * 64 + o],        a0);
      a1 = fmaf(W1[f * 256 + h + 1], W2[(h + 1) * 64 + o],  a1);
      a2 = fmaf(W1[f * 256 + h + 2], W2[(h + 2) * 64 + o],  a2);
      a3 = fmaf(W1[f * 256 + h + 3], W2[(h + 3) * 64 + o],  a3);
    }
    wcB[f * 64 + o] = f2bf_s((a0 + a1) + (a2 + a3));
  } else if (bx == 272) {
    int f = threadIdx.x;
    if (f < 64) {
      float a0 = 0.f, a1 = 0.f, a2 = 0.f, a3 = 0.f;
      for (int h = 0; h < 256; h += 4) {
        a0 = fmaf(W1[f * 256 + h],     b2[h],     a0);
        a1 = fmaf(W1[f * 256 + h + 1], b2[h + 1], a1);
        a2 = fmaf(W1[f * 256 + h + 2], b2[h + 2], a2);
        a3 = fmaf(W1[f * 256 + h + 3], b2[h + 3], a3);
      }
      uF[f] = (a0 + a1) + (a2 + a3);
    }
  } else if (bx < 281) {
    int idx = (bx - 273) * 256 + threadIdx.x;  // [0,2048)
    *(short8*)(w1B + (size_t)idx * 8) = pack8f(W1 + (size_t)idx * 8);
  } else {
    int idx = (bx - 281) * 256 + threadIdx.x;  // [0,2048)
    *(short8*)(w2B + (size_t)idx * 8) = pack8f(W2 + (size_t)idx * 8);
  }
}

// ---------------------------------------------------------------------------
// lstm: LDS-free. grid 256, 512 thr (8 waves). Block: 64 samples x 1024 cols.
// Wave wv owns cols = 4 gates x [wv*32, wv*32+32) -> disjoint, no sharing.
// A-frag: 32B/lane coalesced (128B/row); B-frag: 16B/lane (64B/row, L2-hot).
// No barriers -> compiler pipelines the fully-static K-loop with vmcnt.
// ---------------------------------------------------------------------------
__global__ __launch_bounds__(512, 2) void lstm_kernel(
    const float* __restrict__ x, const float* __restrict__ hp,
    const float* __restrict__ cp, const unsigned short* __restrict__ wsB,
    const float* __restrict__ bih, const float* __restrict__ bhh,
    float* __restrict__ out) {
  const int tid = threadIdx.x;
  const int lane = tid & 63;
  const int wv = tid >> 6;          // 0..7
  const int s = lane & 15, q = lane >> 4;
  const int mb = blockIdx.x * 64;
  const int hb = wv * 32;

  f32x4 acc[4][8];  // [mt][gate*2 + hsub]
#pragma unroll
  for (int mt = 0; mt < 4; ++mt)
#pragma unroll
    for (int tn = 0; tn < 8; ++tn) acc[mt][tn] = (f32x4){0.f, 0.f, 0.f, 0.f};

  for (int kt = 0; kt < 16; ++kt) {
    const float* srcA = (kt < 8) ? x : hp;
    const int kl = (kt * 32) & 255;
    short8 af[4];
#pragma unroll
    for (int mt = 0; mt < 4; ++mt)
      af[mt] = pack8f(srcA + (size_t)(mb + mt * 16 + s) * 256 + kl + q * 8);
#pragma unroll
    for (int tn = 0; tn < 8; ++tn) {
      const int t = (tn >> 1) * 256 + hb + (tn & 1) * 16 + s;
      short8 bfr = *(const short8*)(wsB + (size_t)t * 512 + kt * 32 + q * 8);
#pragma unroll
      for (int mt = 0; mt < 4; ++mt)
        acc[mt][tn] =
            __builtin_amdgcn_mfma_f32_16x16x32_bf16(af[mt], bfr, acc[mt][tn], 0, 0, 0);
    }
  }

  // fused epilogue: thread covers rows mt*16+q*4+r, cols gate*256+hb+hsub*16+s
#pragma unroll
  for (int mt = 0; mt < 4; ++mt)
#pragma unroll
    for (int hsub = 0; hsub < 2; ++hsub)
#pragma unroll
      for (int r = 0; r < 4; ++r) {
        int sample = mb + mt * 16 + q * 4 + r;
        int h = hb + hsub * 16 + s;
        float gi = acc[mt][0 + hsub][r] + bih[h] + bhh[h];
        float gf = acc[mt][2 + hsub][r] + bih[256 + h] + bhh[256 + h];
        float gg = acc[mt][4 + hsub][r] + bih[512 + h] + bhh[512 + h];
        float go = acc[mt][6 + hsub][r] + bih[768 + h] + bhh[768 + h];
        float iv = fast_sigmoid(gi), fv = fast_sigmoid(gf);
        float gv = fast_tanh(gg), ov = fast_sigmoid(go);
        float c = fv * cp[(size_t)sample * 256 + h] + iv * gv;
        float hv = ov * fast_tanh(c);
        out[(size_t)B_N * H_N + (size_t)sample * 256 + h] = c;
        out[(size_t)sample * 256 + h] = hv;
      }
}

// ---------------------------------------------------------------------------
// ode: zero-exchange per-wave G-space dopri5 (R10-verified algebra/layout).
// 8 samples/wave, grid 2048 -> 2 waves/SIMD. Lanes s>=8 compute clamped
// duplicates (never stored) purely to fill the MFMA; B-cols 8-15 are junk.
// ---------------------------------------------------------------------------
__global__ __launch_bounds__(64) void ode_kernel(
    float* __restrict__ out, const float* __restrict__ ts,
    const unsigned short* __restrict__ wcB, const float* __restrict__ uF,
    const unsigned short* __restrict__ w1B, const unsigned short* __restrict__ w2B,
    const float* __restrict__ b1, const float* __restrict__ b2) {
  const int lane = threadIdx.x;
  const int s = lane & 15, q = lane >> 4;
  const int bb = blockIdx.x * 8;
  const int sc = (s < 8) ? s : 7;      // clamped sample offset for loads
  const bool live = (s < 8);

  // permuted A-row feature for tile i at lane-row s
  auto grow = [&](int i) {
    return (i >> 1) * 32 + ((s >> 2) * 8) + (i & 1) * 4 + (s & 3);
  };
  // base feature of this thread's owned f32x4 in tile i
  auto fbase = [&](int i) { return (i >> 1) * 32 + q * 8 + (i & 1) * 4; };

  short8 wcf[4][2];
#pragma unroll
  for (int i = 0; i < 4; ++i) {
    const int gr = grow(i);
#pragma unroll
    for (int kt = 0; kt < 2; ++kt)
      wcf[i][kt] = *(const short8*)(wcB + (size_t)gr * 64 + kt * 32 + q * 8);
  }
  f32x4 b1v[4], u4[4];
#pragma unroll
  for (int i = 0; i < 4; ++i) {
    b1v[i] = *(const f32x4*)(b1 + fbase(i));
    u4[i] = *(const f32x4*)(uF + fbase(i));
  }
  const float dt = ts[bb + sc] * 0.125f;

  // G0 = y0 @ W1^T, then fold b1 into G (track Ghat = G + b1)
  f32x4 G[4];
#pragma unroll
  for (int i = 0; i < 4; ++i) G[i] = (f32x4){0.f, 0.f, 0.f, 0.f};
#pragma unroll
  for (int kt = 0; kt < 8; ++kt) {
    short8 yf = pack8f(out + (size_t)(bb + sc) * 256 + kt * 32 + q * 8);
#pragma unroll
    for (int i = 0; i < 4; ++i) {
      short8 w1f =
          *(const short8*)(w1B + (size_t)grow(i) * 256 + kt * 32 + q * 8);
      G[i] = __builtin_amdgcn_mfma_f32_16x16x32_bf16(w1f, yf, G[i], 0, 0, 0);
    }
  }
#pragma unroll
  for (int i = 0; i < 4; ++i) G[i] += b1v[i];  // Ghat

  auto wcmm = [&](const f32x4 (&zc)[4], f32x4 (&o)[4]) {
    short8 zf0 = pack8v(zc[0], zc[1]);
    short8 zf1 = pack8v(zc[2], zc[3]);
#pragma unroll
    for (int i = 0; i < 4; ++i) {
      f32x4 a = (f32x4){0.f, 0.f, 0.f, 0.f};
      a = __builtin_amdgcn_mfma_f32_16x16x32_bf16(wcf[i][0], zf0, a, 0, 0, 0);
      a = __builtin_amdgcn_mfma_f32_16x16x32_bf16(wcf[i][1], zf1, a, 0, 0, 0);
      o[i] = a;
    }
  };
  auto stage = [&](const f32x4 (&zc)[4], float cj, f32x4 (&zo)[4]) {
    f32x4 o[4];
    wcmm(zc, o);
#pragma unroll
    for (int i = 0; i < 4; ++i)
#pragma unroll
      for (int r = 0; r < 4; ++r)
        zo[i][r] = fast_tanh(fmaf(dt, fmaf(cj, u4[i][r], o[i][r]), G[i][r]));
  };

  const float A31 = 3.f / 40.f, A32 = 9.f / 40.f;
  const float A41 = 44.f / 45.f, A42 = -56.f / 15.f, A43 = 32.f / 9.f;
  const float A51 = 19372.f / 6561.f, A52 = -25360.f / 2187.f,
              A53 = 64448.f / 6561.f, A54 = -212.f / 729.f;
  const float A61 = 9017.f / 3168.f, A62 = -355.f / 33.f, A63 = 46732.f / 5247.f,
              A64 = 49.f / 176.f, A65 = -5103.f / 18656.f;
  const float C1 = 35.f / 384.f, C3 = 500.f / 1113.f, C4 = 125.f / 192.f,
              C5 = -2187.f / 6784.f, C6 = 11.f / 84.f;

  f32x4 SC[4];
#pragma unroll
  for (int i = 0; i < 4; ++i) SC[i] = (f32x4){0.f, 0.f, 0.f, 0.f};
  f32x4 z1[4], z2[4], z3[4], z4[4], z5[4], zc[4];

  for (int st = 0; st < 8; ++st) {
#pragma unroll
    for (int i = 0; i < 4; ++i)
#pragma unroll
      for (int r = 0; r < 4; ++r) z1[i][r] = fast_tanh(G[i][r]);

#pragma unroll
    for (int i = 0; i < 4; ++i) zc[i] = 0.2f * z1[i];
    stage(zc, 0.2f, z2);
#pragma unroll
    for (int i = 0; i < 4; ++i) zc[i] = A31 * z1[i] + A32 * z2[i];
    stage(zc, 0.3f, z3);
#pragma unroll
    for (int i = 0; i < 4; ++i) zc[i] = A41 * z1[i] + A42 * z2[i] + A43 * z3[i];
    stage(zc, 0.8f, z4);
#pragma unroll
    for (int i = 0; i < 4; ++i)
      zc[i] = A51 * z1[i] + A52 * z2[i] + A53 * z3[i] + A54 * z4[i];
    stage(zc, 8.f / 9.f, z5);
#pragma unroll
    for (int i = 0; i < 4; ++i)
      zc[i] = A61 * z1[i] + A62 * z2[i] + A63 * z3[i] + A64 * z4[i] + A65 * z5[i];
    // stage 6 fused: z6 transient, output-combo built in place
    {
      f32x4 o[4];
      wcmm(zc, o);
#pragma unroll
      for (int i = 0; i < 4; ++i)
#pragma unroll
        for (int r = 0; r < 4; ++r) {
          float z6v = fast_tanh(fmaf(dt, u4[i][r] + o[i][r], G[i][r]));
          zc[i][r] = C1 * z1[i][r] + C3 * z3[i][r] + C4 * z4[i][r] +
                     C5 * z5[i][r] + C6 * z6v;
        }
    }
    // G += dt*(u + zC@Wc^T); SC += zC   (b1 fold invariant under +=)
    {
      f32x4 o6[4];
      wcmm(zc, o6);
#pragma unroll
      for (int i = 0; i < 4; ++i) {
        SC[i] += zc[i];
#pragma unroll
        for (int r = 0; r < 4; ++r)
          G[i][r] = fmaf(dt, u4[i][r] + o6[i][r], G[i][r]);
      }
    }
  }

  // epilogue: y = y0 + dt*(8*b2 + SC@W2^T); SC frags owned directly
  {
    short8 sf0 = pack8v(SC[0], SC[1]);
    short8 sf1 = pack8v(SC[2], SC[3]);
#pragma unroll
    for (int ft = 0; ft < 16; ++ft) {
      short8 w2a = *(const short8*)(w2B + (size_t)(ft * 16 + s) * 64 + q * 8);
      short8 w2b = *(const short8*)(w2B + (size_t)(ft * 16 + s) * 64 + 32 + q * 8);
      f32x4 a = (f32x4){0.f, 0.f, 0.f, 0.f};
      a = __builtin_amdgcn_mfma_f32_16x16x32_bf16(w2a, sf0, a, 0, 0, 0);
      a = __builtin_amdgcn_mfma_f32_16x16x32_bf16(w2b, sf1, a, 0, 0, 0);
      f32x4 y0 = *(const f32x4*)(out + (size_t)(bb + sc) * 256 + ft * 16 + q * 4);
      f32x4 b2v = *(const f32x4*)(b2 + ft * 16 + q * 4);
#pragma unroll
      for (int r = 0; r < 4; ++r)
        y0[r] = fmaf(dt, fmaf(8.f, b2v[r], a[r]), y0[r]);
      if (live)
        *(f32x4*)(out + (size_t)(bb + s) * 256 + ft * 16 + q * 4) = y0;
    }
  }
}

extern "C" void kernel_launch(void* const* d_in, const int* in_sizes, int n_in,
                              void* d_out, int out_size, void* d_ws, size_t ws_size,
                              hipStream_t stream) {
  const float* x   = (const float*)d_in[0];
  const float* hp  = (const float*)d_in[1];
  const float* cp  = (const float*)d_in[2];
  const float* ts  = (const float*)d_in[3];
  const float* Wih = (const float*)d_in[4];
  const float* Whh = (const float*)d_in[5];
  const float* bih = (const float*)d_in[6];
  const float* bhh = (const float*)d_in[7];
  const float* W1  = (const float*)d_in[8];
  const float* b1  = (const float*)d_in[9];
  const float* W2  = (const float*)d_in[10];
  const float* b2  = (const float*)d_in[11];
  float* out = (float*)d_out;

  unsigned short* wsB = (unsigned short*)d_ws;                       // 1 MB
  unsigned short* wcB = (unsigned short*)((char*)d_ws + 1048576);    // 8 KB
  float* uF = (float*)((char*)d_ws + 1048576 + 8192);                // 256 B
  unsigned short* w1B = (unsigned short*)((char*)d_ws + 1048576 + 16384);  // 32 KB
  unsigned short* w2B = (unsigned short*)((char*)d_ws + 1048576 + 49152);  // 32 KB

  prep_kernel<<<289, 256, 0, stream>>>(Wih, Whh, W1, W2, b2, wsB, wcB, uF, w1B, w2B);
  lstm_kernel<<<256, 512, 0, stream>>>(x, hp, cp, wsB, bih, bhh, out);
  ode_kernel<<<2048, 64, 0, stream>>>(out, ts, wcB, uF, w1B, w2B, b1, b2);
}

// Round 12
// 78.478 us; speedup vs baseline: 1.7994x; 1.7994x over previous
//
#include <hip/hip_runtime.h>
#include <hip/hip_bf16.h>

// ODELSTMCell: B=16384, I=256, H=256, OH=64, 8 fixed dopri5 steps.
// prep_kernel : wsB=[W_ih|W_hh] bf16; Wc=W1@W2 bf16; u=b2@W1^T f32;
//               w1B=W1 bf16; w2B=W2 bf16.
// lstm_kernel : R8 2-phase LDS pipeline + T4 counted-vmcnt 2-barrier loop
//               (never drains vmcnt(0) mid-loop; prefetch spans barriers).
// ode_kernel  : R10-verified zero-exchange per-wave G-space dopri5,
//               16 samples/wave, grid 1024.

#define B_N 16384
#define H_N 256

typedef __attribute__((ext_vector_type(8))) short short8;          // 8 x bf16
typedef __attribute__((ext_vector_type(4))) unsigned short u16x4;  // 4 x bf16
typedef __attribute__((ext_vector_type(4))) float f32x4;

__device__ __forceinline__ unsigned short f2bf_s(float x) {
  __hip_bfloat16 h = __float2bfloat16(x);
  return *reinterpret_cast<unsigned short*>(&h);
}

__device__ __forceinline__ short8 pack8f(const float* p) {
  const f32x4 a = *(const f32x4*)p;
  const f32x4 b = *(const f32x4*)(p + 4);
  short8 r;
  r[0] = (short)f2bf_s(a[0]); r[1] = (short)f2bf_s(a[1]);
  r[2] = (short)f2bf_s(a[2]); r[3] = (short)f2bf_s(a[3]);
  r[4] = (short)f2bf_s(b[0]); r[5] = (short)f2bf_s(b[1]);
  r[6] = (short)f2bf_s(b[2]); r[7] = (short)f2bf_s(b[3]);
  return r;
}

// two f32x4 registers -> 8 bf16 fragment
__device__ __forceinline__ short8 pack8v(f32x4 a, f32x4 b) {
  short8 r;
  r[0] = (short)f2bf_s(a[0]); r[1] = (short)f2bf_s(a[1]);
  r[2] = (short)f2bf_s(a[2]); r[3] = (short)f2bf_s(a[3]);
  r[4] = (short)f2bf_s(b[0]); r[5] = (short)f2bf_s(b[1]);
  r[6] = (short)f2bf_s(b[2]); r[7] = (short)f2bf_s(b[3]);
  return r;
}

__device__ __forceinline__ float fast_sigmoid(float x) {
  return __builtin_amdgcn_rcpf(1.f + __expf(-x));
}
// clamp-free: e^inf -> rcp 0 -> 1; e^-inf -> 0 -> -1  (exact limits)
__device__ __forceinline__ float fast_tanh(float x) {
  float e = __expf(2.f * x);
  return 1.f - 2.f * __builtin_amdgcn_rcpf(e + 1.f);
}

__device__ __forceinline__ void gl_lds16(const void* g, void* l) {
  __builtin_amdgcn_global_load_lds(
      (const __attribute__((address_space(1))) void*)g,
      (__attribute__((address_space(3))) void*)l, 16, 0, 0);
}

// ---------------------------------------------------------------------------
// prep: [0,256) wsB; [256,272) Wc=W1@W2; 272 u=b2@W1^T; [273,281) w1B; [281,289) w2B
// ---------------------------------------------------------------------------
__global__ __launch_bounds__(256) void prep_kernel(
    const float* __restrict__ Wih, const float* __restrict__ Whh,
    const float* __restrict__ W1, const float* __restrict__ W2,
    const float* __restrict__ b2,
    unsigned short* __restrict__ wsB, unsigned short* __restrict__ wcB,
    float* __restrict__ uF, unsigned short* __restrict__ w1B,
    unsigned short* __restrict__ w2B) {
  const int bx = blockIdx.x;
  if (bx < 256) {
    int idx = bx * 256 + threadIdx.x;
    int n = idx >> 6, c = idx & 63, k = c * 8;
    const float* src = (k < 256) ? (Wih + (size_t)n * 256 + k)
                                 : (Whh + (size_t)n * 256 + (k - 256));
    *(short8*)(wsB + (size_t)n * 512 + k) = pack8f(src);
  } else if (bx < 272) {
    int idx = (bx - 256) * 256 + threadIdx.x;  // [0,4096)
    int f = idx >> 6, o = idx & 63;
    float a0 = 0.f, a1 = 0.f, a2 = 0.f, a3 = 0.f;
    for (int h = 0; h < 256; h += 4) {
      a0 = fmaf(W1[f * 256 + h],     W2[h * 64 + o],        a0);
      a1 = fmaf(W1[f * 256 + h + 1], W2[(h + 1) * 64 + o],  a1);
      a2 = fmaf(W1[f * 256 + h + 2], W2[(h + 2) * 64 + o],  a2);
      a3 = fmaf(W1[f * 256 + h + 3], W2[(h + 3) * 64 + o],  a3);
    }
    wcB[f * 64 + o] = f2bf_s((a0 + a1) + (a2 + a3));
  } else if (bx == 272) {
    int f = threadIdx.x;
    if (f < 64) {
      float a0 = 0.f, a1 = 0.f, a2 = 0.f, a3 = 0.f;
      for (int h = 0; h < 256; h += 4) {
        a0 = fmaf(W1[f * 256 + h],     b2[h],     a0);
        a1 = fmaf(W1[f * 256 + h + 1], b2[h + 1], a1);
        a2 = fmaf(W1[f * 256 + h + 2], b2[h + 2], a2);
        a3 = fmaf(W1[f * 256 + h + 3], b2[h + 3], a3);
      }
      uF[f] = (a0 + a1) + (a2 + a3);
    }
  } else if (bx < 281) {
    int idx = (bx - 273) * 256 + threadIdx.x;  // [0,2048)
    *(short8*)(w1B + (size_t)idx * 8) = pack8f(W1 + (size_t)idx * 8);
  } else {
    int idx = (bx - 281) * 256 + threadIdx.x;  // [0,2048)
    *(short8*)(w2B + (size_t)idx * 8) = pack8f(W2 + (size_t)idx * 8);
  }
}

// ---------------------------------------------------------------------------
// lstm: grid (128, 4), 512 thr (8 waves = 4 rowgrp x 2 colgrp).
// K=512 in 16 steps of 32, double-buffered LDS.
// Loop (T4 counted): STAGE(next) -> vmcnt(4) -> barrier -> compute -> barrier.
// In-loop vmcnt never drains to 0: next tile's 4 loads stay in flight across
// both barriers and land during the following iteration's compute.
// ---------------------------------------------------------------------------
__global__ __launch_bounds__(512, 4) void lstm_kernel(
    const float* __restrict__ x, const float* __restrict__ hp,
    const float* __restrict__ cp, const unsigned short* __restrict__ wsB,
    const float* __restrict__ bih, const float* __restrict__ bhh,
    float* __restrict__ out) {
  __shared__ __align__(16) float As2[2][128 * 32];           // 16KB x2
  __shared__ __align__(16) unsigned short Bs2[2][256 * 32];  // 16KB x2

  const int tid = threadIdx.x;
  const int lane = tid & 63;
  const int wv = tid >> 6;          // 0..7
  const int rg = wv >> 1;           // 0..3 (row group)
  const int cg = wv & 1;            // 0..1 (col group)
  const int s = lane & 15, q = lane >> 4;
  const int mb = blockIdx.x * 128;
  const int hb = blockIdx.y * 64;

  f32x4 acc[2][8];  // [mt][gate*2 + ntl]
#pragma unroll
  for (int mt = 0; mt < 2; ++mt)
#pragma unroll
    for (int tn = 0; tn < 8; ++tn) acc[mt][tn] = (f32x4){0.f, 0.f, 0.f, 0.f};

  // staging roles (per buffer = 16 x 1KB wave-chunks; wave wv does 2)
  const int c16a = wv * 2;
  const int rowA0 = c16a * 8 + (lane >> 3);
  const int gcA = (lane & 7) ^ (rowA0 & 7);
  const int rowB0 = c16a * 16 + (lane >> 2);
  const int rowB1 = rowB0 + 16;
  const int gcB0 = (lane & 3) ^ ((rowB0 >> 1) & 3);
  const int gcB1 = (lane & 3) ^ ((rowB1 >> 1) & 3);
  const int grB0 = (rowB0 >> 6) * 256 + hb + (rowB0 & 63);
  const int grB1 = (rowB1 >> 6) * 256 + hb + (rowB1 & 63);

  auto STAGE = [&](int buf, int kt) {  // 4 gl_lds per thread
    const float* srcA = (kt < 8) ? x : hp;
    const int kl = (kt * 32) & 255;
    gl_lds16(srcA + (size_t)(mb + rowA0) * 256 + kl + gcA * 4,
             (char*)As2[buf] + c16a * 1024);
    gl_lds16(srcA + (size_t)(mb + rowA0 + 8) * 256 + kl + gcA * 4,
             (char*)As2[buf] + (c16a + 1) * 1024);
    gl_lds16(wsB + (size_t)grB0 * 512 + kt * 32 + gcB0 * 8,
             (char*)Bs2[buf] + c16a * 1024);
    gl_lds16(wsB + (size_t)grB1 * 512 + kt * 32 + gcB1 * 8,
             (char*)Bs2[buf] + (c16a + 1) * 1024);
  };

  auto COMPUTE = [&](int buf) {
#pragma unroll
    for (int kk = 0; kk < 2; ++kk) {
      short8 af[2];
#pragma unroll
      for (int mt = 0; mt < 2; ++mt) {
        const int ar = rg * 32 + mt * 16 + s;
        const char* ap = (const char*)As2[buf] + ar * 128;
        float tmp[8];
        *(f32x4*)tmp = *(const f32x4*)(ap + (((kk * 8 + q * 2) ^ (ar & 7)) << 4) -
                                       (kk * 8 ^ 0) * 0);
        // NOTE: layout identical to R8: chunk index c0 = kk*8?? — see below
        af[mt] = af[mt];
      }
    }
  };
  (void)0;

  // --- R8-exact compute body (kept inline for clarity/safety) ---
  auto COMPUTE8 = [&](int buf) {
#pragma unroll
    for (int kk = 0; kk < 2; ++kk) {
      short8 af[2];
#pragma unroll
      for (int mt = 0; mt < 2; ++mt) {
        const int ar = rg * 32 + mt * 16 + s;
        const char* ap = (const char*)As2[buf] + ar * 128;
        float tmp[8];
        *(f32x4*)tmp = *(const f32x4*)(ap + (((q * 2) ^ (ar & 7)) << 4));
        *(f32x4*)(tmp + 4) =
            *(const f32x4*)(ap + (((q * 2 + 1) ^ (ar & 7)) << 4));
        af[mt] = pack8f(tmp);
      }
      const char* bp = (const char*)Bs2[buf];
#pragma unroll
      for (int tn = 0; tn < 8; ++tn) {
        const int t = (tn >> 1) * 64 + cg * 32 + (tn & 1) * 16 + s;
        short8 bfr = *(const short8*)(bp + t * 64 + ((q ^ ((t >> 1) & 3)) << 4));
        acc[0][tn] =
            __builtin_amdgcn_mfma_f32_16x16x32_bf16(af[0], bfr, acc[0][tn], 0, 0, 0);
        acc[1][tn] =
            __builtin_amdgcn_mfma_f32_16x16x32_bf16(af[1], bfr, acc[1][tn], 0, 0, 0);
      }
      if (kk == 0) continue;  // single K=32 per buffer step handled below
    }
  };
  (void)0;

  // The R8 kernel computed K=32 per buffer (one kk pass). Keep that exactly:
  auto COMPUTE32 = [&](int buf) {
    short8 af[2];
#pragma unroll
    for (int mt = 0; mt < 2; ++mt) {
      const int ar = rg * 32 + mt * 16 + s;
      const char* ap = (const char*)As2[buf] + ar * 128;
      float tmp[8];
      *(f32x4*)tmp = *(const f32x4*)(ap + (((q * 2) ^ (ar & 7)) << 4));
      *(f32x4*)(tmp + 4) = *(const f32x4*)(ap + (((q * 2 + 1) ^ (ar & 7)) << 4));
      af[mt] = pack8f(tmp);
    }
    const char* bp = (const char*)Bs2[buf];
#pragma unroll
    for (int tn = 0; tn < 8; ++tn) {
      const int t = (tn >> 1) * 64 + cg * 32 + (tn & 1) * 16 + s;
      short8 bfr = *(const short8*)(bp + t * 64 + ((q ^ ((t >> 1) & 3)) << 4));
      acc[0][tn] =
          __builtin_amdgcn_mfma_f32_16x16x32_bf16(af[0], bfr, acc[0][tn], 0, 0, 0);
      acc[1][tn] =
          __builtin_amdgcn_mfma_f32_16x16x32_bf16(af[1], bfr, acc[1][tn], 0, 0, 0);
    }
  };

  STAGE(0, 0);
#pragma unroll 1
  for (int kt = 0; kt < 15; ++kt) {
    const int buf = kt & 1;
    STAGE(buf ^ 1, kt + 1);
    asm volatile("s_waitcnt vmcnt(4)" ::: "memory");  // buf's loads landed
    __builtin_amdgcn_s_barrier();                     // ...for ALL waves
    __builtin_amdgcn_sched_barrier(0);
    COMPUTE32(buf);
    __builtin_amdgcn_s_barrier();  // readers done before next STAGE overwrites
  }
  asm volatile("s_waitcnt vmcnt(0)" ::: "memory");
  __builtin_amdgcn_s_barrier();
  __builtin_amdgcn_sched_barrier(0);
  COMPUTE32(1);  // kt = 15

  // fused epilogue
#pragma unroll
  for (int mt = 0; mt < 2; ++mt)
#pragma unroll
    for (int ntl = 0; ntl < 2; ++ntl)
#pragma unroll
      for (int r = 0; r < 4; ++r) {
        int sample = mb + rg * 32 + mt * 16 + q * 4 + r;
        int h = hb + cg * 32 + ntl * 16 + s;
        float gi = acc[mt][0 + ntl][r] + bih[h] + bhh[h];
        float gf = acc[mt][2 + ntl][r] + bih[256 + h] + bhh[256 + h];
        float gg = acc[mt][4 + ntl][r] + bih[512 + h] + bhh[512 + h];
        float go = acc[mt][6 + ntl][r] + bih[768 + h] + bhh[768 + h];
        float iv = fast_sigmoid(gi), fv = fast_sigmoid(gf);
        float gv = fast_tanh(gg), ov = fast_sigmoid(go);
        float c = fv * cp[(size_t)sample * 256 + h] + iv * gv;
        float hv = ov * fast_tanh(c);
        out[(size_t)B_N * H_N + (size_t)sample * 256 + h] = c;
        out[(size_t)sample * 256 + h] = hv;
      }
}

// ---------------------------------------------------------------------------
// ode (R10-verified): zero-exchange per-wave G-space dopri5.
// 64 thr = 1 wave = 16 samples; feature permutation g(i,m) makes each
// thread's MFMA outputs exactly its next B-fragment. No LDS, no barriers.
// ---------------------------------------------------------------------------
__global__ __launch_bounds__(64) void ode_kernel(
    float* __restrict__ out, const float* __restrict__ ts,
    const unsigned short* __restrict__ wcB, const float* __restrict__ uF,
    const unsigned short* __restrict__ w1B, const unsigned short* __restrict__ w2B,
    const float* __restrict__ b1, const float* __restrict__ b2) {
  const int lane = threadIdx.x;
  const int s = lane & 15, q = lane >> 4;
  const int bb = blockIdx.x * 16;

  auto grow = [&](int i) {
    return (i >> 1) * 32 + ((s >> 2) * 8) + (i & 1) * 4 + (s & 3);
  };
  auto fbase = [&](int i) { return (i >> 1) * 32 + q * 8 + (i & 1) * 4; };

  short8 wcf[4][2];
#pragma unroll
  for (int i = 0; i < 4; ++i) {
    const int gr = grow(i);
#pragma unroll
    for (int kt = 0; kt < 2; ++kt)
      wcf[i][kt] = *(const short8*)(wcB + (size_t)gr * 64 + kt * 32 + q * 8);
  }
  f32x4 b1v[4], u4[4];
#pragma unroll
  for (int i = 0; i < 4; ++i) {
    b1v[i] = *(const f32x4*)(b1 + fbase(i));
    u4[i] = *(const f32x4*)(uF + fbase(i));
  }
  const float dt = ts[bb + s] * 0.125f;

  f32x4 G[4];
#pragma unroll
  for (int i = 0; i < 4; ++i) G[i] = (f32x4){0.f, 0.f, 0.f, 0.f};
#pragma unroll
  for (int kt = 0; kt < 8; ++kt) {
    short8 yf = pack8f(out + (size_t)(bb + s) * 256 + kt * 32 + q * 8);
#pragma unroll
    for (int i = 0; i < 4; ++i) {
      short8 w1f =
          *(const short8*)(w1B + (size_t)grow(i) * 256 + kt * 32 + q * 8);
      G[i] = __builtin_amdgcn_mfma_f32_16x16x32_bf16(w1f, yf, G[i], 0, 0, 0);
    }
  }
#pragma unroll
  for (int i = 0; i < 4; ++i) G[i] += b1v[i];  // Ghat = G + b1

  auto wcmm = [&](const f32x4 (&zc)[4], f32x4 (&o)[4]) {
    short8 zf0 = pack8v(zc[0], zc[1]);
    short8 zf1 = pack8v(zc[2], zc[3]);
#pragma unroll
    for (int i = 0; i < 4; ++i) {
      f32x4 a = (f32x4){0.f, 0.f, 0.f, 0.f};
      a = __builtin_amdgcn_mfma_f32_16x16x32_bf16(wcf[i][0], zf0, a, 0, 0, 0);
      a = __builtin_amdgcn_mfma_f32_16x16x32_bf16(wcf[i][1], zf1, a, 0, 0, 0);
      o[i] = a;
    }
  };
  auto stage = [&](const f32x4 (&zc)[4], float cj, f32x4 (&zo)[4]) {
    f32x4 o[4];
    wcmm(zc, o);
#pragma unroll
    for (int i = 0; i < 4; ++i)
#pragma unroll
      for (int r = 0; r < 4; ++r)
        zo[i][r] = fast_tanh(fmaf(dt, fmaf(cj, u4[i][r], o[i][r]), G[i][r]));
  };

  const float A31 = 3.f / 40.f, A32 = 9.f / 40.f;
  const float A41 = 44.f / 45.f, A42 = -56.f / 15.f, A43 = 32.f / 9.f;
  const float A51 = 19372.f / 6561.f, A52 = -25360.f / 2187.f,
              A53 = 64448.f / 6561.f, A54 = -212.f / 729.f;
  const float A61 = 9017.f / 3168.f, A62 = -355.f / 33.f, A63 = 46732.f / 5247.f,
              A64 = 49.f / 176.f, A65 = -5103.f / 18656.f;
  const float C1 = 35.f / 384.f, C3 = 500.f / 1113.f, C4 = 125.f / 192.f,
              C5 = -2187.f / 6784.f, C6 = 11.f / 84.f;

  f32x4 SC[4];
#pragma unroll
  for (int i = 0; i < 4; ++i) SC[i] = (f32x4){0.f, 0.f, 0.f, 0.f};
  f32x4 z1[4], z2[4], z3[4], z4[4], z5[4], zc[4];

  for (int st = 0; st < 8; ++st) {
#pragma unroll
    for (int i = 0; i < 4; ++i)
#pragma unroll
      for (int r = 0; r < 4; ++r) z1[i][r] = fast_tanh(G[i][r]);

#pragma unroll
    for (int i = 0; i < 4; ++i) zc[i] = 0.2f * z1[i];
    stage(zc, 0.2f, z2);
#pragma unroll
    for (int i = 0; i < 4; ++i) zc[i] = A31 * z1[i] + A32 * z2[i];
    stage(zc, 0.3f, z3);
#pragma unroll
    for (int i = 0; i < 4; ++i) zc[i] = A41 * z1[i] + A42 * z2[i] + A43 * z3[i];
    stage(zc, 0.8f, z4);
#pragma unroll
    for (int i = 0; i < 4; ++i)
      zc[i] = A51 * z1[i] + A52 * z2[i] + A53 * z3[i] + A54 * z4[i];
    stage(zc, 8.f / 9.f, z5);
#pragma unroll
    for (int i = 0; i < 4; ++i)
      zc[i] = A61 * z1[i] + A62 * z2[i] + A63 * z3[i] + A64 * z4[i] + A65 * z5[i];
    {
      f32x4 o[4];
      wcmm(zc, o);
#pragma unroll
      for (int i = 0; i < 4; ++i)
#pragma unroll
        for (int r = 0; r < 4; ++r) {
          float z6v = fast_tanh(fmaf(dt, u4[i][r] + o[i][r], G[i][r]));
          zc[i][r] = C1 * z1[i][r] + C3 * z3[i][r] + C4 * z4[i][r] +
                     C5 * z5[i][r] + C6 * z6v;
        }
    }
    {
      f32x4 o6[4];
      wcmm(zc, o6);
#pragma unroll
      for (int i = 0; i < 4; ++i) {
        SC[i] += zc[i];
#pragma unroll
        for (int r = 0; r < 4; ++r)
          G[i][r] = fmaf(dt, u4[i][r] + o6[i][r], G[i][r]);
      }
    }
  }

  // epilogue: y = y0 + dt*(8*b2 + SC@W2^T)
  {
    short8 sf0 = pack8v(SC[0], SC[1]);
    short8 sf1 = pack8v(SC[2], SC[3]);
#pragma unroll
    for (int ft = 0; ft < 16; ++ft) {
      short8 w2a = *(const short8*)(w2B + (size_t)(ft * 16 + s) * 64 + q * 8);
      short8 w2b = *(const short8*)(w2B + (size_t)(ft * 16 + s) * 64 + 32 + q * 8);
      f32x4 a = (f32x4){0.f, 0.f, 0.f, 0.f};
      a = __builtin_amdgcn_mfma_f32_16x16x32_bf16(w2a, sf0, a, 0, 0, 0);
      a = __builtin_amdgcn_mfma_f32_16x16x32_bf16(w2b, sf1, a, 0, 0, 0);
      f32x4 y0 = *(const f32x4*)(out + (size_t)(bb + s) * 256 + ft * 16 + q * 4);
      f32x4 b2v = *(const f32x4*)(b2 + ft * 16 + q * 4);
#pragma unroll
      for (int r = 0; r < 4; ++r)
        y0[r] = fmaf(dt, fmaf(8.f, b2v[r], a[r]), y0[r]);
      *(f32x4*)(out + (size_t)(bb + s) * 256 + ft * 16 + q * 4) = y0;
    }
  }
}

extern "C" void kernel_launch(void* const* d_in, const int* in_sizes, int n_in,
                              void* d_out, int out_size, void* d_ws, size_t ws_size,
                              hipStream_t stream) {
  const float* x   = (const float*)d_in[0];
  const float* hp  = (const float*)d_in[1];
  const float* cp  = (const float*)d_in[2];
  const float* ts  = (const float*)d_in[3];
  const float* Wih = (const float*)d_in[4];
  const float* Whh = (const float*)d_in[5];
  const float* bih = (const float*)d_in[6];
  const float* bhh = (const float*)d_in[7];
  const float* W1  = (const float*)d_in[8];
  const float* b1  = (const float*)d_in[9];
  const float* W2  = (const float*)d_in[10];
  const float* b2  = (const float*)d_in[11];
  float* out = (float*)d_out;

  unsigned short* wsB = (unsigned short*)d_ws;                       // 1 MB
  unsigned short* wcB = (unsigned short*)((char*)d_ws + 1048576);    // 8 KB
  float* uF = (float*)((char*)d_ws + 1048576 + 8192);                // 256 B
  unsigned short* w1B = (unsigned short*)((char*)d_ws + 1048576 + 16384);  // 32 KB
  unsigned short* w2B = (unsigned short*)((char*)d_ws + 1048576 + 49152);  // 32 KB

  prep_kernel<<<289, 256, 0, stream>>>(Wih, Whh, W1, W2, b2, wsB, wcB, uF, w1B, w2B);
  lstm_kernel<<<dim3(128, 4), 512, 0, stream>>>(x, hp, cp, wsB, bih, bhh, out);
  ode_kernel<<<1024, 64, 0, stream>>>(out, ts, wcB, uF, w1B, w2B, b1, b2);
}

// Round 13
// 78.414 us; speedup vs baseline: 1.8009x; 1.0008x over previous
//
#include <hip/hip_runtime.h>
#include <hip/hip_bf16.h>

// ODELSTMCell: B=16384, I=256, H=256, OH=64, 8 fixed dopri5 steps.
// prep_kernel : wsB=[W_ih|W_hh] bf16; Wc=W1@W2 bf16; u=b2@W1^T f32;
//               w1B=W1 bf16; w2B=W2 bf16.
// lstm_kernel : m97-shaped: 128x256 block, 8 waves (2x4), BK=64 as two 32-k
//               sub-tiles (64B rows, R12-verified banking), bf16 A via
//               reg-stage+cvt+swizzled ds_write, B via pre-swizzled gl_lds,
//               2 barriers per BK=64 (16 total).
// ode_kernel  : R10/R12-verified zero-exchange per-wave G-space dopri5.

#define B_N 16384
#define H_N 256

typedef __attribute__((ext_vector_type(8))) short short8;          // 8 x bf16
typedef __attribute__((ext_vector_type(4))) unsigned short u16x4;  // 4 x bf16
typedef __attribute__((ext_vector_type(4))) float f32x4;

__device__ __forceinline__ unsigned short f2bf_s(float x) {
  __hip_bfloat16 h = __float2bfloat16(x);
  return *reinterpret_cast<unsigned short*>(&h);
}

__device__ __forceinline__ short8 pack8f(const float* p) {
  const f32x4 a = *(const f32x4*)p;
  const f32x4 b = *(const f32x4*)(p + 4);
  short8 r;
  r[0] = (short)f2bf_s(a[0]); r[1] = (short)f2bf_s(a[1]);
  r[2] = (short)f2bf_s(a[2]); r[3] = (short)f2bf_s(a[3]);
  r[4] = (short)f2bf_s(b[0]); r[5] = (short)f2bf_s(b[1]);
  r[6] = (short)f2bf_s(b[2]); r[7] = (short)f2bf_s(b[3]);
  return r;
}

__device__ __forceinline__ short8 pack8v(f32x4 a, f32x4 b) {
  short8 r;
  r[0] = (short)f2bf_s(a[0]); r[1] = (short)f2bf_s(a[1]);
  r[2] = (short)f2bf_s(a[2]); r[3] = (short)f2bf_s(a[3]);
  r[4] = (short)f2bf_s(b[0]); r[5] = (short)f2bf_s(b[1]);
  r[6] = (short)f2bf_s(b[2]); r[7] = (short)f2bf_s(b[3]);
  return r;
}

__device__ __forceinline__ float fast_sigmoid(float x) {
  return __builtin_amdgcn_rcpf(1.f + __expf(-x));
}
// clamp-free: e^inf -> rcp 0 -> 1; e^-inf -> 0 -> -1  (exact limits)
__device__ __forceinline__ float fast_tanh(float x) {
  float e = __expf(2.f * x);
  return 1.f - 2.f * __builtin_amdgcn_rcpf(e + 1.f);
}

__device__ __forceinline__ void gl_lds16(const void* g, void* l) {
  __builtin_amdgcn_global_load_lds(
      (const __attribute__((address_space(1))) void*)g,
      (__attribute__((address_space(3))) void*)l, 16, 0, 0);
}

// ---------------------------------------------------------------------------
// prep: [0,256) wsB; [256,272) Wc=W1@W2; 272 u=b2@W1^T; [273,281) w1B; [281,289) w2B
// ---------------------------------------------------------------------------
__global__ __launch_bounds__(256) void prep_kernel(
    const float* __restrict__ Wih, const float* __restrict__ Whh,
    const float* __restrict__ W1, const float* __restrict__ W2,
    const float* __restrict__ b2,
    unsigned short* __restrict__ wsB, unsigned short* __restrict__ wcB,
    float* __restrict__ uF, unsigned short* __restrict__ w1B,
    unsigned short* __restrict__ w2B) {
  const int bx = blockIdx.x;
  if (bx < 256) {
    int idx = bx * 256 + threadIdx.x;
    int n = idx >> 6, c = idx & 63, k = c * 8;
    const float* src = (k < 256) ? (Wih + (size_t)n * 256 + k)
                                 : (Whh + (size_t)n * 256 + (k - 256));
    *(short8*)(wsB + (size_t)n * 512 + k) = pack8f(src);
  } else if (bx < 272) {
    int idx = (bx - 256) * 256 + threadIdx.x;  // [0,4096)
    int f = idx >> 6, o = idx & 63;
    float a0 = 0.f, a1 = 0.f, a2 = 0.f, a3 = 0.f;
    for (int h = 0; h < 256; h += 4) {
      a0 = fmaf(W1[f * 256 + h],     W2[h * 64 + o],        a0);
      a1 = fmaf(W1[f * 256 + h + 1], W2[(h + 1) * 64 + o],  a1);
      a2 = fmaf(W1[f * 256 + h + 2], W2[(h + 2) * 64 + o],  a2);
      a3 = fmaf(W1[f * 256 + h + 3], W2[(h + 3) * 64 + o],  a3);
    }
    wcB[f * 64 + o] = f2bf_s((a0 + a1) + (a2 + a3));
  } else if (bx == 272) {
    int f = threadIdx.x;
    if (f < 64) {
      float a0 = 0.f, a1 = 0.f, a2 = 0.f, a3 = 0.f;
      for (int h = 0; h < 256; h += 4) {
        a0 = fmaf(W1[f * 256 + h],     b2[h],     a0);
        a1 = fmaf(W1[f * 256 + h + 1], b2[h + 1], a1);
        a2 = fmaf(W1[f * 256 + h + 2], b2[h + 2], a2);
        a3 = fmaf(W1[f * 256 + h + 3], b2[h + 3], a3);
      }
      uF[f] = (a0 + a1) + (a2 + a3);
    }
  } else if (bx < 281) {
    int idx = (bx - 273) * 256 + threadIdx.x;  // [0,2048)
    *(short8*)(w1B + (size_t)idx * 8) = pack8f(W1 + (size_t)idx * 8);
  } else {
    int idx = (bx - 281) * 256 + threadIdx.x;  // [0,2048)
    *(short8*)(w2B + (size_t)idx * 8) = pack8f(W2 + (size_t)idx * 8);
  }
}

// ---------------------------------------------------------------------------
// lstm: grid (128, 4), 512 thr (8 waves = 2 rg x 4 cg).
// Block: 128 samples x 256 cols (4 gates x 64 h). Wave: 64 rows x 64 cols.
// LDS: Abf[2][128][32] bf16 (8KB x2), Bbf[2][256][32] bf16 (16KB x2) = 48KB.
// Per kt (BK=64): stage both sub-tiles -> barrier -> 2x(frag+16 MFMA) -> barrier.
// Swizzle (R12-verified banking): phys_chunk = log_chunk ^ ((row>>1)&3).
// ---------------------------------------------------------------------------
__global__ __launch_bounds__(512, 4) void lstm_kernel(
    const float* __restrict__ x, const float* __restrict__ hp,
    const float* __restrict__ cp, const unsigned short* __restrict__ wsB,
    const float* __restrict__ bih, const float* __restrict__ bhh,
    float* __restrict__ out) {
  __shared__ __align__(16) unsigned short Abf[2][128 * 32];  // 8KB x2
  __shared__ __align__(16) unsigned short Bbf[2][256 * 32];  // 16KB x2

  const int tid = threadIdx.x;
  const int lane = tid & 63;
  const int wv = tid >> 6;        // 0..7
  const int rg = wv >> 2;         // 0..1 (64-row half)
  const int cg = wv & 3;          // 0..3 (16-h strip within 64)
  const int s = lane & 15, q = lane >> 4;
  const int mb = blockIdx.x * 128;
  const int hb = blockIdx.y;      // 0..3 (64-h strip)

  f32x4 acc[4][4];  // [mt][gate]
#pragma unroll
  for (int mt = 0; mt < 4; ++mt)
#pragma unroll
    for (int g = 0; g < 4; ++g) acc[mt][g] = (f32x4){0.f, 0.f, 0.f, 0.f};

  // A staging role: row rA = tid>>2, chunk q4 = tid&3 (k = q4*8..q4*8+7)
  const int rA = tid >> 2, q4 = tid & 3;
  const int physA = q4 ^ ((rA >> 1) & 3);

  for (int kt = 0; kt < 8; ++kt) {
    const float* srcA = (kt < 4) ? x : hp;
    const int kl = (kt * 64) & 255;

    // --- B: pre-swizzled-source gl_lds (4 per wave: 2 subs x 2 row-blocks) ---
#pragma unroll
    for (int u = 0; u < 2; ++u)
#pragma unroll
      for (int j = 0; j < 2; ++j) {
        int c = wv * 32 + j * 16 + (lane >> 2);        // block-col row in Bbf
        int lc = (lane & 3) ^ ((c >> 1) & 3);          // logical chunk
        int n = (c >> 6) * 256 + hb * 64 + (c & 63);   // global gate-row
        gl_lds16(wsB + (size_t)n * 512 + kt * 64 + u * 32 + lc * 8,
                 (char*)Bbf[u] + (wv * 32 + j * 16) * 64);
      }
    // --- A: reg-stage f32 -> bf16, swizzled ds_write ---
#pragma unroll
    for (int u = 0; u < 2; ++u) {
      const float* ap = srcA + (size_t)(mb + rA) * 256 + kl + u * 32 + q4 * 8;
      f32x4 v0 = *(const f32x4*)ap;
      f32x4 v1 = *(const f32x4*)(ap + 4);
      *(short8*)((char*)Abf[u] + rA * 64 + physA * 16) = pack8v(v0, v1);
    }
    __syncthreads();

    // --- compute: 2 sub-tiles x 16 MFMA ---
#pragma unroll
    for (int u = 0; u < 2; ++u) {
      short8 af[4];
#pragma unroll
      for (int mt = 0; mt < 4; ++mt) {
        int r = rg * 64 + mt * 16 + s;
        af[mt] = *(const short8*)((char*)Abf[u] + r * 64 +
                                  ((q ^ ((r >> 1) & 3)) << 4));
      }
#pragma unroll
      for (int g = 0; g < 4; ++g) {
        int c = (g * 4 + cg) * 16 + s;
        short8 bfr = *(const short8*)((char*)Bbf[u] + c * 64 +
                                      ((q ^ ((c >> 1) & 3)) << 4));
#pragma unroll
        for (int mt = 0; mt < 4; ++mt)
          acc[mt][g] =
              __builtin_amdgcn_mfma_f32_16x16x32_bf16(af[mt], bfr, acc[mt][g], 0, 0, 0);
      }
    }
    __syncthreads();
  }

  // --- fused epilogue ---
#pragma unroll
  for (int mt = 0; mt < 4; ++mt)
#pragma unroll
    for (int r = 0; r < 4; ++r) {
      int sample = mb + rg * 64 + mt * 16 + q * 4 + r;
      int h = hb * 64 + cg * 16 + s;
      float gi = acc[mt][0][r] + bih[h] + bhh[h];
      float gf = acc[mt][1][r] + bih[256 + h] + bhh[256 + h];
      float gg = acc[mt][2][r] + bih[512 + h] + bhh[512 + h];
      float go = acc[mt][3][r] + bih[768 + h] + bhh[768 + h];
      float iv = fast_sigmoid(gi), fv = fast_sigmoid(gf);
      float gv = fast_tanh(gg), ov = fast_sigmoid(go);
      float c = fv * cp[(size_t)sample * 256 + h] + iv * gv;
      float hv = ov * fast_tanh(c);
      out[(size_t)B_N * H_N + (size_t)sample * 256 + h] = c;
      out[(size_t)sample * 256 + h] = hv;
    }
}

// ---------------------------------------------------------------------------
// ode (R10/R12-verified): zero-exchange per-wave G-space dopri5.
// 64 thr = 1 wave = 16 samples; feature permutation g(i,m) makes each
// thread's MFMA outputs exactly its next B-fragment. No LDS, no barriers.
// ---------------------------------------------------------------------------
__global__ __launch_bounds__(64) void ode_kernel(
    float* __restrict__ out, const float* __restrict__ ts,
    const unsigned short* __restrict__ wcB, const float* __restrict__ uF,
    const unsigned short* __restrict__ w1B, const unsigned short* __restrict__ w2B,
    const float* __restrict__ b1, const float* __restrict__ b2) {
  const int lane = threadIdx.x;
  const int s = lane & 15, q = lane >> 4;
  const int bb = blockIdx.x * 16;

  auto grow = [&](int i) {
    return (i >> 1) * 32 + ((s >> 2) * 8) + (i & 1) * 4 + (s & 3);
  };
  auto fbase = [&](int i) { return (i >> 1) * 32 + q * 8 + (i & 1) * 4; };

  short8 wcf[4][2];
#pragma unroll
  for (int i = 0; i < 4; ++i) {
    const int gr = grow(i);
#pragma unroll
    for (int kt = 0; kt < 2; ++kt)
      wcf[i][kt] = *(const short8*)(wcB + (size_t)gr * 64 + kt * 32 + q * 8);
  }
  f32x4 b1v[4], u4[4];
#pragma unroll
  for (int i = 0; i < 4; ++i) {
    b1v[i] = *(const f32x4*)(b1 + fbase(i));
    u4[i] = *(const f32x4*)(uF + fbase(i));
  }
  const float dt = ts[bb + s] * 0.125f;

  f32x4 G[4];
#pragma unroll
  for (int i = 0; i < 4; ++i) G[i] = (f32x4){0.f, 0.f, 0.f, 0.f};
#pragma unroll
  for (int kt = 0; kt < 8; ++kt) {
    short8 yf = pack8f(out + (size_t)(bb + s) * 256 + kt * 32 + q * 8);
#pragma unroll
    for (int i = 0; i < 4; ++i) {
      short8 w1f =
          *(const short8*)(w1B + (size_t)grow(i) * 256 + kt * 32 + q * 8);
      G[i] = __builtin_amdgcn_mfma_f32_16x16x32_bf16(w1f, yf, G[i], 0, 0, 0);
    }
  }
#pragma unroll
  for (int i = 0; i < 4; ++i) G[i] += b1v[i];  // Ghat = G + b1

  auto wcmm = [&](const f32x4 (&zc)[4], f32x4 (&o)[4]) {
    short8 zf0 = pack8v(zc[0], zc[1]);
    short8 zf1 = pack8v(zc[2], zc[3]);
#pragma unroll
    for (int i = 0; i < 4; ++i) {
      f32x4 a = (f32x4){0.f, 0.f, 0.f, 0.f};
      a = __builtin_amdgcn_mfma_f32_16x16x32_bf16(wcf[i][0], zf0, a, 0, 0, 0);
      a = __builtin_amdgcn_mfma_f32_16x16x32_bf16(wcf[i][1], zf1, a, 0, 0, 0);
      o[i] = a;
    }
  };
  auto stage = [&](const f32x4 (&zc)[4], float cj, f32x4 (&zo)[4]) {
    f32x4 o[4];
    wcmm(zc, o);
#pragma unroll
    for (int i = 0; i < 4; ++i)
#pragma unroll
      for (int r = 0; r < 4; ++r)
        zo[i][r] = fast_tanh(fmaf(dt, fmaf(cj, u4[i][r], o[i][r]), G[i][r]));
  };

  const float A31 = 3.f / 40.f, A32 = 9.f / 40.f;
  const float A41 = 44.f / 45.f, A42 = -56.f / 15.f, A43 = 32.f / 9.f;
  const float A51 = 19372.f / 6561.f, A52 = -25360.f / 2187.f,
              A53 = 64448.f / 6561.f, A54 = -212.f / 729.f;
  const float A61 = 9017.f / 3168.f, A62 = -355.f / 33.f, A63 = 46732.f / 5247.f,
              A64 = 49.f / 176.f, A65 = -5103.f / 18656.f;
  const float C1 = 35.f / 384.f, C3 = 500.f / 1113.f, C4 = 125.f / 192.f,
              C5 = -2187.f / 6784.f, C6 = 11.f / 84.f;

  f32x4 SC[4];
#pragma unroll
  for (int i = 0; i < 4; ++i) SC[i] = (f32x4){0.f, 0.f, 0.f, 0.f};
  f32x4 z1[4], z2[4], z3[4], z4[4], z5[4], zc[4];

  for (int st = 0; st < 8; ++st) {
#pragma unroll
    for (int i = 0; i < 4; ++i)
#pragma unroll
      for (int r = 0; r < 4; ++r) z1[i][r] = fast_tanh(G[i][r]);

#pragma unroll
    for (int i = 0; i < 4; ++i) zc[i] = 0.2f * z1[i];
    stage(zc, 0.2f, z2);
#pragma unroll
    for (int i = 0; i < 4; ++i) zc[i] = A31 * z1[i] + A32 * z2[i];
    stage(zc, 0.3f, z3);
#pragma unroll
    for (int i = 0; i < 4; ++i) zc[i] = A41 * z1[i] + A42 * z2[i] + A43 * z3[i];
    stage(zc, 0.8f, z4);
#pragma unroll
    for (int i = 0; i < 4; ++i)
      zc[i] = A51 * z1[i] + A52 * z2[i] + A53 * z3[i] + A54 * z4[i];
    stage(zc, 8.f / 9.f, z5);
#pragma unroll
    for (int i = 0; i < 4; ++i)
      zc[i] = A61 * z1[i] + A62 * z2[i] + A63 * z3[i] + A64 * z4[i] + A65 * z5[i];
    {
      f32x4 o[4];
      wcmm(zc, o);
#pragma unroll
      for (int i = 0; i < 4; ++i)
#pragma unroll
        for (int r = 0; r < 4; ++r) {
          float z6v = fast_tanh(fmaf(dt, u4[i][r] + o[i][r], G[i][r]));
          zc[i][r] = C1 * z1[i][r] + C3 * z3[i][r] + C4 * z4[i][r] +
                     C5 * z5[i][r] + C6 * z6v;
        }
    }
    {
      f32x4 o6[4];
      wcmm(zc, o6);
#pragma unroll
      for (int i = 0; i < 4; ++i) {
        SC[i] += zc[i];
#pragma unroll
        for (int r = 0; r < 4; ++r)
          G[i][r] = fmaf(dt, u4[i][r] + o6[i][r], G[i][r]);
      }
    }
  }

  // epilogue: y = y0 + dt*(8*b2 + SC@W2^T)
  {
    short8 sf0 = pack8v(SC[0], SC[1]);
    short8 sf1 = pack8v(SC[2], SC[3]);
#pragma unroll
    for (int ft = 0; ft < 16; ++ft) {
      short8 w2a = *(const short8*)(w2B + (size_t)(ft * 16 + s) * 64 + q * 8);
      short8 w2b = *(const short8*)(w2B + (size_t)(ft * 16 + s) * 64 + 32 + q * 8);
      f32x4 a = (f32x4){0.f, 0.f, 0.f, 0.f};
      a = __builtin_amdgcn_mfma_f32_16x16x32_bf16(w2a, sf0, a, 0, 0, 0);
      a = __builtin_amdgcn_mfma_f32_16x16x32_bf16(w2b, sf1, a, 0, 0, 0);
      f32x4 y0 = *(const f32x4*)(out + (size_t)(bb + s) * 256 + ft * 16 + q * 4);
      f32x4 b2v = *(const f32x4*)(b2 + ft * 16 + q * 4);
#pragma unroll
      for (int r = 0; r < 4; ++r)
        y0[r] = fmaf(dt, fmaf(8.f, b2v[r], a[r]), y0[r]);
      *(f32x4*)(out + (size_t)(bb + s) * 256 + ft * 16 + q * 4) = y0;
    }
  }
}

extern "C" void kernel_launch(void* const* d_in, const int* in_sizes, int n_in,
                              void* d_out, int out_size, void* d_ws, size_t ws_size,
                              hipStream_t stream) {
  const float* x   = (const float*)d_in[0];
  const float* hp  = (const float*)d_in[1];
  const float* cp  = (const float*)d_in[2];
  const float* ts  = (const float*)d_in[3];
  const float* Wih = (const float*)d_in[4];
  const float* Whh = (const float*)d_in[5];
  const float* bih = (const float*)d_in[6];
  const float* bhh = (const float*)d_in[7];
  const float* W1  = (const float*)d_in[8];
  const float* b1  = (const float*)d_in[9];
  const float* W2  = (const float*)d_in[10];
  const float* b2  = (const float*)d_in[11];
  float* out = (float*)d_out;

  unsigned short* wsB = (unsigned short*)d_ws;                       // 1 MB
  unsigned short* wcB = (unsigned short*)((char*)d_ws + 1048576);    // 8 KB
  float* uF = (float*)((char*)d_ws + 1048576 + 8192);                // 256 B
  unsigned short* w1B = (unsigned short*)((char*)d_ws + 1048576 + 16384);  // 32 KB
  unsigned short* w2B = (unsigned short*)((char*)d_ws + 1048576 + 49152);  // 32 KB

  prep_kernel<<<289, 256, 0, stream>>>(Wih, Whh, W1, W2, b2, wsB, wcB, uF, w1B, w2B);
  lstm_kernel<<<dim3(128, 4), 512, 0, stream>>>(x, hp, cp, wsB, bih, bhh, out);
  ode_kernel<<<1024, 64, 0, stream>>>(out, ts, wcB, uF, w1B, w2B, b1, b2);
}